// Round 13
// baseline (78.225 us; speedup 1.0000x reference)
//
#include <hip/hip_runtime.h>
#include <math.h>

#define HH 32
#define WW 32
#define CIN 64
#define NO 64
#define NCK 576                 // CIN*9
#define X_ELEMS 262144
#define NP2 8192                // pixel-halves (4096 pixels x 2 c-halves)
#define STRIDE_E 296            // worklist entries per pixel-half (288 max + pad)

// ws float-offsets
#define WS_W    0               // Wz[ck][o] = -SZ*theta[o][ck]  (36864)
#define WS_TAU  36864           // tau[ck] = SZ*min_o theta - 8, +64 pad(1e30)
#define WS_N    37504           // 8192 ints: rounds per pixel-half
#define WS_LC   45696           // int  worklist [NP2][STRIDE_E] : ck
#define WS_LX   (WS_LC + NP2 * STRIDE_E)   // float worklist: xs = SZ*x

__device__ __forceinline__ float fexp2(float x) {
#if __has_builtin(__builtin_amdgcn_exp2f)
    return __builtin_amdgcn_exp2f(x);
#else
    return exp2f(x);
#endif
}
__device__ __forceinline__ float flog2(float x) {
#if __has_builtin(__builtin_amdgcn_logf)
    return __builtin_amdgcn_logf(x);
#else
    return log2f(x);
#endif
}

__global__ __launch_bounds__(256) void prep_kernel(const float* __restrict__ theta,
                                                   float* __restrict__ ws) {
    constexpr float SZ = 19.235933878519512f;    // log2(e)/0.075
    const int b = blockIdx.x, t = threadIdx.x;
    if (b < 144) {                               // W transform + in-wave tau min
        int i = b * 256 + t;                     // i = ck*64 + o; lanes are o
        int o = i & 63, ck = i >> 6;
        float th = theta[o * NCK + ck];
        ws[WS_W + i] = -SZ * th;
        float mn = th;                           // wave-min over the 64 o's
#pragma unroll
        for (int s = 32; s > 0; s >>= 1)
            mn = fminf(mn, __shfl_xor(mn, s, 64));
        if (o == 0) ws[WS_TAU + ck] = SZ * mn - 8.0f;   // active iff z >= -8
    } else {                                     // tau pad: never active
        if (t < 64) ws[WS_TAU + NCK + t] = 1e30f;
    }
}

// Extraction pass: wave = pixel-half, lanes 0..62 test 7ch x 9taps per ballot;
// actives compacted to a per-pixel-half worklist via mbcnt (consecutive
// addresses -> coalesced). No ctz loop, no readlane -- straight-line.
__global__ __launch_bounds__(512) void build_kernel(const float* __restrict__ x,
                                                    float* __restrict__ ws) {
    constexpr float SZ = 19.235933878519512f;
    const int t    = threadIdx.x;
    const int lane = t & 63;
    const int wv   = __builtin_amdgcn_readfirstlane(t >> 6);
    const int p2   = (int)blockIdx.x * 8 + wv;
    const int pix  = p2 >> 1, half = p2 & 1;
    const int n  = pix >> 10;
    const int ho = (pix >> 5) & 31;
    const int wo = pix & 31;
    const int c0 = half * 32;

    int l = lane;
    int c_off = l / 9; if (c_off > 6) c_off = 6;
    int k = l - 9 * c_off; if (k > 8) k = 8;
    int di = k / 3, dj = k - 3 * (k / 3);
    int h = ho + di - 1, w_ = wo + dj - 1;
    bool sval = (h >= 0) && (h < HH) && (w_ >= 0) && (w_ < WW);
    int hc = min(max(h, 0), HH - 1), wc = min(max(w_, 0), WW - 1);
    // pad taps: xs = 0 == exact x=0 contribution if active; skipped if tau>0
    float msc = ((l < 63) && sval) ? SZ : 0.0f;

    int gidx = n * (CIN * HH * WW) + (c0 + c_off) * 1024 + hc * WW + wc;
    const float* tw = ws + WS_TAU + c0 * 9;

    int*   listC = (int*)ws + WS_LC + p2 * STRIDE_E;
    float* listX = ws + WS_LX + p2 * STRIDE_E;
    int cnt = 0;

    float xv = x[min(gidx, X_ELEMS - 1)];
    float tv = tw[l];

    for (int cb = 0; cb < 32; cb += 7) {
        int cc = 32 - cb; if (cc > 7) cc = 7;
        int gidx2 = gidx + 7 * 1024;
        const float* tw2 = tw + 63;
        float xvn = xv, tvn = tv;
        if (cb + 7 < 32) { xvn = x[min(gidx2, X_ELEMS - 1)]; tvn = tw2[l]; }

        float xs = xv * msc;
        bool a = (xs >= tv) && (l < cc * 9);
        unsigned long long act = __ballot(a);
        unsigned lo32 = (unsigned)act, hi32 = (unsigned)(act >> 32);
        int idx = __builtin_amdgcn_mbcnt_hi(hi32,
                      __builtin_amdgcn_mbcnt_lo(lo32, 0));
        if (a) {
            listC[cnt + idx] = (c0 + cb) * 9 + l;   // ck
            listX[cnt + idx] = xs;                  // SZ*x
        }
        cnt += __popcll(act);
        gidx = gidx2; tw = tw2; xv = xvn; tv = tvn;
    }
    // pad to a multiple of 4 with exact-zero dummies (z ~ -1e5 -> exp2 -> 0)
    int padn = (-cnt) & 3;
    if (lane < padn) { listC[cnt + lane] = 0; listX[cnt + lane] = -100000.0f; }
    cnt += padn;
    if (lane == 0) ((int*)ws)[WS_N + p2] = cnt >> 2;   // rounds
}

// Evaluation pass: wave = pixel-half, lane = o. Fixed-trip loop over worklist
// quads (uniform 16B loads, prefetched one round ahead); 4 W-row loads + 4
// bodies per round. No ballot/ctz/readlane in the hot loop.
__global__ __launch_bounds__(512) void ekv_kernel(
        const float* __restrict__ ws, float* __restrict__ out) {
    constexpr float C2 = 1.2726342e-3f;          // 2^(-D2), D2 = 0.5/(0.075*ln2)
    constexpr float OS = 0.020018875579925058f;  // ln2^2 * 2e-6 * 500000/24

    __shared__ float part[4][64];

    const int t    = threadIdx.x;
    const int lane = t & 63;
    const int wv   = __builtin_amdgcn_readfirstlane(t >> 6);
    const int p2   = (int)blockIdx.x * 8 + wv;
    const int pix  = p2 >> 1, half = p2 & 1;
    const int px   = wv >> 1;                    // pixel slot within block
    const int n  = pix >> 10;
    const int ho = (pix >> 5) & 31;
    const int wo = pix & 31;

    const int rounds = ((const int*)ws)[WS_N + p2];          // uniform
    const int4*   LC = (const int4*)((const int*)ws + WS_LC + p2 * STRIDE_E);
    const float4* LX = (const float4*)(ws + WS_LX + p2 * STRIDE_E);
    const float* wsW = ws + WS_W;

    float accF = 0.f, accR = 0.f;

#define EKV_BODY(SX, WV)                                                   \
    {                                                                      \
        float z  = (WV) + (SX);      /* SZ*(x - theta) */                  \
        float e  = fexp2(z);                                               \
        float f  = flog2(1.0f + e);                                        \
        float rr = flog2(fmaf(C2, e, 1.0f));                               \
        accF = fmaf(f, f, accF);                                           \
        accR = fmaf(rr, rr, accR);                                         \
    }

    if (rounds > 0) {
        int4   cq = LC[0];
        float4 xq = LX[0];
        for (int r = 0; r < rounds; ++r) {
            int4 cqn = cq; float4 xqn = xq;
            if (r + 1 < rounds) { cqn = LC[r + 1]; xqn = LX[r + 1]; }
            // 4 coalesced W-row loads issued before any body
            float W0 = wsW[(cq.x << 6) + lane];
            float W1 = wsW[(cq.y << 6) + lane];
            float W2 = wsW[(cq.z << 6) + lane];
            float W3 = wsW[(cq.w << 6) + lane];
            EKV_BODY(xq.x, W0)
            EKV_BODY(xq.y, W1)
            EKV_BODY(xq.z, W2)
            EKV_BODY(xq.w, W3)
            cq = cqn; xq = xqn;
        }
    }
#undef EKV_BODY

    float p = accF - accR;
    if (half == 1) part[px][lane] = p;
    __syncthreads();
    if (half == 0)
        out[((n * NO + lane) * HH + ho) * WW + wo] = (p + part[px][lane]) * OS;
}

extern "C" void kernel_launch(void* const* d_in, const int* in_sizes, int n_in,
                              void* d_out, int out_size, void* d_ws, size_t ws_size,
                              hipStream_t stream) {
    const float* x     = (const float*)d_in[0];   // (4,64,32,32) fp32
    const float* theta = (const float*)d_in[1];   // (64,64,3,3) fp32
    float* out = (float*)d_out;                   // (4,64,32,32) fp32
    float* ws  = (float*)d_ws;

    prep_kernel <<<145, 256, 0, stream>>>(theta, ws);
    build_kernel<<<1024, 512, 0, stream>>>(x, ws);    // worklist extraction
    ekv_kernel  <<<1024, 512, 0, stream>>>(ws, out);  // worklist evaluation
}

// Round 14
// 72.461 us; speedup vs baseline: 1.0795x; 1.0795x over previous
//
#include <hip/hip_runtime.h>
#include <math.h>

#define HH 32
#define WW 32
#define CIN 64
#define NO 64
#define NCK 576                 // CIN*9
#define X_ELEMS 262144
#define STRIDE_E 292            // LDS worklist entries per pixel-half (288+pad, 16B-aligned rows)

// ws float-offsets
#define WS_W    0               // Wz[ck][o] = -SZ*theta[o][ck]  (36864, coalesced in o)
#define WS_TAU  36864           // tau[ck] = SZ*min_o theta - 8, +64 pad(1e30)

__device__ __forceinline__ float fexp2(float x) {
#if __has_builtin(__builtin_amdgcn_exp2f)
    return __builtin_amdgcn_exp2f(x);
#else
    return exp2f(x);
#endif
}
__device__ __forceinline__ float flog2(float x) {
#if __has_builtin(__builtin_amdgcn_logf)
    return __builtin_amdgcn_logf(x);
#else
    return log2f(x);
#endif
}

__global__ __launch_bounds__(256) void prep_kernel(const float* __restrict__ theta,
                                                   float* __restrict__ ws) {
    constexpr float SZ = 19.235933878519512f;    // log2(e)/0.075
    const int b = blockIdx.x, t = threadIdx.x;
    if (b < 144) {                               // W transform + in-wave tau min
        int i = b * 256 + t;                     // i = ck*64 + o; lanes are o
        int o = i & 63, ck = i >> 6;
        float th = theta[o * NCK + ck];
        ws[WS_W + i] = -SZ * th;
        float mn = th;                           // wave-min over the 64 o's
#pragma unroll
        for (int s = 32; s > 0; s >>= 1)
            mn = fminf(mn, __shfl_xor(mn, s, 64));
        if (o == 0) ws[WS_TAU + ck] = SZ * mn - 8.0f;   // active iff z >= -8
    } else {                                     // tau pad: never active
        if (t < 64) ws[WS_TAU + NCK + t] = 1e30f;
    }
}

// Single main kernel: block = 512 thr = 8 waves = 4 pixels x 2 c-halves.
// Phase A (per wave, no barrier needed -- wave consumes its own list): test
// 7ch x 9taps per ballot, mbcnt-compact actives into an LDS worklist.
// Phase B (per wave): fixed-trip loop over worklist quads (uniform
// ds_read_b128, prefetched), 4 pipelined global W-row loads + 4 exp2/log2
// bodies per round. No ballot/ctz/readlane in the evaluation loop.
__global__ __launch_bounds__(512) void ekv_kernel(
        const float* __restrict__ x, const float* __restrict__ ws,
        float* __restrict__ out) {
    constexpr float SZ = 19.235933878519512f;    // log2(e)/0.075
    constexpr float C2 = 1.2726342e-3f;          // 2^(-D2), D2 = 0.5/(0.075*ln2)
    constexpr float OS = 0.020018875579925058f;  // ln2^2 * 2e-6 * 500000/24

    __shared__ int   lc[8][STRIDE_E];            // ck worklists (per wave)
    __shared__ float lx[8][STRIDE_E];            // xs worklists
    __shared__ float part[4][64];

    const int t    = threadIdx.x;
    const int lane = t & 63;
    const int wv   = __builtin_amdgcn_readfirstlane(t >> 6);  // 0..7
    const int p2   = (int)blockIdx.x * 8 + wv;   // pixel-half id
    const int pix  = p2 >> 1, half = p2 & 1;
    const int px   = wv >> 1;                    // pixel slot within block
    const int n  = pix >> 10;
    const int ho = (pix >> 5) & 31;
    const int wo = pix & 31;
    const int c0 = half * 32;

    // ---- Phase A: build this wave's worklist in LDS ----
    int l = lane;
    int c_off = l / 9; if (c_off > 6) c_off = 6;
    int k = l - 9 * c_off; if (k > 8) k = 8;
    int di = k / 3, dj = k - 3 * (k / 3);
    int h = ho + di - 1, w_ = wo + dj - 1;
    bool sval = (h >= 0) && (h < HH) && (w_ >= 0) && (w_ < WW);
    int hc = min(max(h, 0), HH - 1), wc = min(max(w_, 0), WW - 1);
    // pad taps: xs = 0 == exact x=0 contribution if ever active; else skipped
    float msc = ((l < 63) && sval) ? SZ : 0.0f;

    int gidx = n * (CIN * HH * WW) + (c0 + c_off) * 1024 + hc * WW + wc;
    const float* tw = ws + WS_TAU + c0 * 9;

    int cnt = 0;
    float xv = x[min(gidx, X_ELEMS - 1)];        // chunk 0 (OOB lanes masked)
    float tv = tw[l];

    for (int cb = 0; cb < 32; cb += 7) {
        int cc = 32 - cb; if (cc > 7) cc = 7;
        int gidx2 = gidx + 7 * 1024;
        const float* tw2 = tw + 63;
        float xvn = xv, tvn = tv;
        if (cb + 7 < 32) { xvn = x[min(gidx2, X_ELEMS - 1)]; tvn = tw2[l]; }

        float xs = xv * msc;                     // SZ*x (pad lanes: 0)
        bool a = (xs >= tv) && (l < cc * 9);
        unsigned long long act = __ballot(a);
        unsigned lo32 = (unsigned)act, hi32 = (unsigned)(act >> 32);
        int idx = __builtin_amdgcn_mbcnt_hi(hi32,
                      __builtin_amdgcn_mbcnt_lo(lo32, 0));
        if (a) {
            lc[wv][cnt + idx] = (c0 + cb) * 9 + l;   // ck
            lx[wv][cnt + idx] = xs;                  // SZ*x
        }
        cnt += (int)__popcll(act);               // uniform across lanes
        gidx = gidx2; tw = tw2; xv = xvn; tv = tvn;
    }
    // pad to a multiple of 4 with exact-zero dummies (z=-1e5 -> exp2 -> 0)
    int padn = (-cnt) & 3;
    if (lane < padn) { lc[wv][cnt + lane] = 0; lx[wv][cnt + lane] = -100000.0f; }
    const int rounds = (cnt + padn) >> 2;        // uniform

    // ---- Phase B: fixed-trip quad evaluation over this wave's list ----
    const int4*   LC = (const int4*)&lc[wv][0];  // rows are 16B-aligned (292*4)
    const float4* LX = (const float4*)&lx[wv][0];
    const float* wsW = ws + WS_W;

    float accF = 0.f, accR = 0.f;

#define EKV_BODY(SX, WV)                                                   \
    {                                                                      \
        float z  = (WV) + (SX);      /* SZ*(x - theta) */                  \
        float e  = fexp2(z);                                               \
        float f  = flog2(1.0f + e);                                        \
        float rr = flog2(fmaf(C2, e, 1.0f));                               \
        accF = fmaf(f, f, accF);                                           \
        accR = fmaf(rr, rr, accR);                                         \
    }

    if (rounds > 0) {
        int4   cq = LC[0];
        float4 xq = LX[0];
        for (int r = 0; r < rounds; ++r) {
            int4 cqn = cq; float4 xqn = xq;
            if (r + 1 < rounds) { cqn = LC[r + 1]; xqn = LX[r + 1]; }
            // 4 coalesced W-row loads issued before any body
            float W0 = wsW[(cq.x << 6) + lane];
            float W1 = wsW[(cq.y << 6) + lane];
            float W2 = wsW[(cq.z << 6) + lane];
            float W3 = wsW[(cq.w << 6) + lane];
            EKV_BODY(xq.x, W0)
            EKV_BODY(xq.y, W1)
            EKV_BODY(xq.z, W2)
            EKV_BODY(xq.w, W3)
            cq = cqn; xq = xqn;
        }
    }
#undef EKV_BODY

    float p = accF - accR;
    if (half == 1) part[px][lane] = p;
    __syncthreads();
    if (half == 0)
        out[((n * NO + lane) * HH + ho) * WW + wo] = (p + part[px][lane]) * OS;
}

extern "C" void kernel_launch(void* const* d_in, const int* in_sizes, int n_in,
                              void* d_out, int out_size, void* d_ws, size_t ws_size,
                              hipStream_t stream) {
    const float* x     = (const float*)d_in[0];   // (4,64,32,32) fp32
    const float* theta = (const float*)d_in[1];   // (64,64,3,3) fp32
    float* out = (float*)d_out;                   // (4,64,32,32) fp32
    float* ws  = (float*)d_ws;

    prep_kernel<<<145, 256, 0, stream>>>(theta, ws);
    ekv_kernel <<<1024, 512, 0, stream>>>(x, ws, out);  // build+eval fused
}